// Round 12
// baseline (576.749 us; speedup 1.0000x reference)
//
#include <hip/hip_runtime.h>
#include <math.h>

constexpr int N_ = 30000;
constexpr int E_ = 300000;
constexpr int SCB = (N_ + 255) / 256;   // 118 scan blocks
constexpr int GB_ = (N_ + 63) / 64;     // 469 GEMM blocks

using f32x4  = __attribute__((ext_vector_type(4))) float;
using bf16x8 = __attribute__((ext_vector_type(8))) short;

__device__ __forceinline__ float4 ldg4(const float* p){ return *reinterpret_cast<const float4*>(p); }

__device__ __forceinline__ unsigned short f2bf(float f){
  union { float f; unsigned int u; } v; v.f = f;
  unsigned int r = v.u + 0x7FFFu + ((v.u >> 16) & 1u);
  return (unsigned short)(r >> 16);
}
__device__ __forceinline__ float bf2f(unsigned short b){
  union { unsigned int u; float f; } v; v.u = ((unsigned int)b) << 16;
  return v.f;
}
__device__ __forceinline__ float sigmoidf_(float x){ return 1.0f/(1.0f + __expf(-x)); }

// ---------------- setup kernels (once per launch) ----------------

// blocks 0..255: bf16 B-fragment weights for MFMA 16x16x32
//   frag element (nt,kt,l,j) = B[k = kt*32 + (l>>4)*8 + j][n = nt*16 + (l&15)]
// block 256: P[j][h]; blocks 257..256+SCB: zero deg; block 257+SCB: zero bn_stats
__global__ void k_wfrag(const float* __restrict__ Wg, const float* __restrict__ Wih,
                        const float* __restrict__ Whh, const float* __restrict__ Wlin,
                        const float* __restrict__ We, const float* __restrict__ a_edge,
                        unsigned short* __restrict__ fG, unsigned short* __restrict__ fI,
                        unsigned short* __restrict__ fH, unsigned short* __restrict__ fL,
                        float* __restrict__ P, int* __restrict__ deg,
                        float* __restrict__ bn_stats){
  if (blockIdx.x == 257 + SCB){
    for (int k = threadIdx.x; k < 768; k += 256) bn_stats[k] = 0.f;
    return;
  }
  if (blockIdx.x >= 257){
    int i = (blockIdx.x - 257)*256 + threadIdx.x;
    if (i < N_) deg[i] = 0;
    return;
  }
  if (blockIdx.x == 256){
    int t = threadIdx.x; if (t >= 48) return;
    int j = t / 3, h = t % 3;
    float s = 0.f;
    for (int c = 0; c < 64; ++c) s += We[j*192 + h*64 + c] * a_edge[h*64 + c];
    P[j*3 + h] = s;
    return;
  }
  int id = blockIdx.x*256 + threadIdx.x;   // 0..65535
  int lid, KT;
  unsigned short* dst; int mode;
  if (id < 12288)      { lid = id;         KT = 2;  dst = fG; mode = 0; }
  else if (id < 24576) { lid = id - 12288; KT = 2;  dst = fI; mode = 1; }
  else if (id < 36864) { lid = id - 24576; KT = 2;  dst = fH; mode = 2; }
  else                 { lid = id - 36864; KT = 14; dst = fL; mode = 3; }
  int j = lid & 7, l = (lid >> 3) & 63, rest = lid >> 9;
  int kt = rest % KT, nt = rest / KT;
  int k = kt*32 + (l>>4)*8 + j;
  int n = nt*16 + (l&15);
  float v;
  if (mode == 0)      v = Wg[k*192 + n];
  else if (mode == 1) v = Wih[n*64 + k];
  else if (mode == 2) v = Whh[n*64 + k];
  else                v = Wlin[k*64 + n];
  dst[lid] = f2bf(v);
}

__global__ void k_hist(const int* __restrict__ ei, int* __restrict__ deg){
  int e = blockIdx.x*256 + threadIdx.x;
  if (e < E_) atomicAdd(&deg[ei[E_ + e]], 1);
}

__global__ void k_scanA(const int* __restrict__ deg, int* __restrict__ partial){
  int i = blockIdx.x*256 + threadIdx.x;
  int v = (i < N_) ? deg[i] : 0;
  #pragma unroll
  for (int off = 1; off < 64; off <<= 1) v += __shfl_xor(v, off);
  __shared__ int ws[4];
  if ((threadIdx.x & 63) == 0) ws[threadIdx.x >> 6] = v;
  __syncthreads();
  if (threadIdx.x == 0) partial[blockIdx.x] = ws[0] + ws[1] + ws[2] + ws[3];
}

__global__ void k_scanB(int* __restrict__ partial, int* __restrict__ row_ptr){
  __shared__ int s[128];
  int t = threadIdx.x;
  int v = (t < SCB) ? partial[t] : 0;
  s[t] = v; __syncthreads();
  for (int off = 1; off < 128; off <<= 1){
    int u = (t >= off) ? s[t-off] : 0;
    __syncthreads();
    s[t] += u;
    __syncthreads();
  }
  if (t < SCB) partial[t] = s[t] - v;   // exclusive
  if (t == 0) row_ptr[N_] = E_;
}

__global__ void k_scanC(const int* __restrict__ deg, const int* __restrict__ partial,
                        int* __restrict__ row_ptr, int* __restrict__ cursor){
  __shared__ int s[256];
  int t = threadIdx.x, i = blockIdx.x*256 + t;
  int v = (i < N_) ? deg[i] : 0;
  s[t] = v; __syncthreads();
  for (int off = 1; off < 256; off <<= 1){
    int u = (t >= off) ? s[t-off] : 0;
    __syncthreads();
    s[t] += u;
    __syncthreads();
  }
  int ex = s[t] - v + partial[blockIdx.x];
  if (i < N_){ row_ptr[i] = ex; cursor[i] = ex; }
}

// fused: edge logit term (edge_attr @ P) + CSR scatter
__global__ void k_scatter(const int* __restrict__ ei, const float* __restrict__ edge_attr,
                          const float* __restrict__ P,
                          int* __restrict__ cursor, int* __restrict__ src_s,
                          float* __restrict__ el_s){
  __shared__ float sP[48];
  int t = threadIdx.x;
  if (t < 48) sP[t] = P[t];
  __syncthreads();
  int e = blockIdx.x*256 + t;
  if (e >= E_) return;
  const float* ea = edge_attr + (size_t)e*16;
  float v[16];
  #pragma unroll
  for (int q = 0; q < 4; ++q){
    float4 f = ldg4(ea + q*4);
    v[q*4+0]=f.x; v[q*4+1]=f.y; v[q*4+2]=f.z; v[q*4+3]=f.w;
  }
  float l0=0.f,l1=0.f,l2=0.f;
  #pragma unroll
  for (int j = 0; j < 16; ++j){
    l0 += v[j]*sP[j*3+0]; l1 += v[j]*sP[j*3+1]; l2 += v[j]*sP[j*3+2];
  }
  int d = ei[E_ + e];
  int p = atomicAdd(&cursor[d], 1);
  src_s[p] = ei[e];
  el_s[p*3+0] = l0; el_s[p*3+1] = l1; el_s[p*3+2] = l2;
}

// ---------------- per-step kernels ----------------

// fused BN(hsrc) + xw = bn(x)@Wg via MFMA + alpha dots; persists fragment
// tile for k_final; xw stored bf16 in 3 per-head planes [h][n][64].
__global__ __launch_bounds__(256) void k_xw(
    const float* __restrict__ hsrc,
    const float* __restrict__ bn_stats,     // slot of previous step
    const float* __restrict__ gamma, const float* __restrict__ beta,
    int gidx, int bn,
    const unsigned short* __restrict__ fG,
    const float* __restrict__ a_src, const float* __restrict__ a_dst,
    unsigned short* __restrict__ xw,        // 3 planes of N*64
    float* __restrict__ asrc, float* __restrict__ adst,
    unsigned short* __restrict__ fr)
{
  __shared__ short sAf[8*64*8];        // A-frag bf16, 8 KB
  __shared__ unsigned short sXW[64*196];
  __shared__ float sSc[64], sSh[64];
  const int t = threadIdx.x;
  const int row0 = blockIdx.x * 64;
  if (t < 64){
    float sc = 1.f, sh = 0.f;
    if (bn){
      float mu  = bn_stats[t] * (1.0f/30000.0f);
      float var = bn_stats[64+t] * (1.0f/30000.0f) - mu*mu;
      float rs = rsqrtf(var + 1e-5f);
      sc = gamma[gidx*64 + t] * rs;
      sh = beta[gidx*64 + t] - mu*sc;
    }
    sSc[t] = sc; sSh[t] = sh;
  }
  __syncthreads();
  {
    const int lr = t >> 4, k4 = (t & 15) * 4;
    const float sc0=sSc[k4],sc1=sSc[k4+1],sc2=sSc[k4+2],sc3=sSc[k4+3];
    const float sh0=sSh[k4],sh1=sSh[k4+1],sh2=sSh[k4+2],sh3=sSh[k4+3];
    const int kt = k4 >> 5, lanew = lr + (((k4>>3)&3)<<4), j0 = k4 & 7;
    #pragma unroll
    for (int i = 0; i < 4; ++i){
      int r = lr + i*16, gr = row0 + r;
      float4 v = make_float4(0.f,0.f,0.f,0.f);
      if (gr < N_){
        v = ldg4(hsrc + (size_t)gr*64 + k4);
        v.x = fmaf(v.x, sc0, sh0); v.y = fmaf(v.y, sc1, sh1);
        v.z = fmaf(v.z, sc2, sh2); v.w = fmaf(v.w, sc3, sh3);
      }
      ushort4 pk; pk.x=f2bf(v.x); pk.y=f2bf(v.y); pk.z=f2bf(v.z); pk.w=f2bf(v.w);
      *reinterpret_cast<ushort4*>(&sAf[((i*2+kt)*64 + lanew)*8 + j0]) = pk;
    }
  }
  __syncthreads();
  // persist the fragment tile for k_final
  {
    bf16x8 v0 = *reinterpret_cast<bf16x8*>(&sAf[t*8]);
    bf16x8 v1 = *reinterpret_cast<bf16x8*>(&sAf[2048 + t*8]);
    bf16x8* g = reinterpret_cast<bf16x8*>(fr + (size_t)blockIdx.x*4096);
    g[t] = v0; g[256 + t] = v1;
  }
  const int w = t >> 6, l = t & 63, q = l >> 4, b = l & 15;
  f32x4 acc[12];
  #pragma unroll
  for (int nt = 0; nt < 12; ++nt) acc[nt] = (f32x4){0.f,0.f,0.f,0.f};
  bf16x8 a0 = *reinterpret_cast<bf16x8*>(&sAf[((w*2+0)*64 + l)*8]);
  bf16x8 a1 = *reinterpret_cast<bf16x8*>(&sAf[((w*2+1)*64 + l)*8]);
  #pragma unroll
  for (int nt = 0; nt < 12; ++nt){
    bf16x8 b0 = *reinterpret_cast<const bf16x8*>(fG + (size_t)((nt*2+0)*64 + l)*8);
    bf16x8 b1 = *reinterpret_cast<const bf16x8*>(fG + (size_t)((nt*2+1)*64 + l)*8);
    acc[nt] = __builtin_amdgcn_mfma_f32_16x16x32_bf16(a0, b0, acc[nt], 0, 0, 0);
    acc[nt] = __builtin_amdgcn_mfma_f32_16x16x32_bf16(a1, b1, acc[nt], 0, 0, 0);
  }
  // attention dots
  float asl[3][4], adl[3][4];
  #pragma unroll
  for (int h = 0; h < 3; ++h)
    #pragma unroll
    for (int u = 0; u < 4; ++u){
      asl[h][u] = a_src[h*64 + u*16 + b];
      adl[h][u] = a_dst[h*64 + u*16 + b];
    }
  #pragma unroll
  for (int r = 0; r < 4; ++r){
    int gr = row0 + w*16 + q*4 + r;
    #pragma unroll
    for (int h = 0; h < 3; ++h){
      float s = 0.f, d = 0.f;
      #pragma unroll
      for (int u = 0; u < 4; ++u){
        s = fmaf(acc[4*h+u][r], asl[h][u], s);
        d = fmaf(acc[4*h+u][r], adl[h][u], d);
      }
      s += __shfl_xor(s,1); s += __shfl_xor(s,2); s += __shfl_xor(s,4); s += __shfl_xor(s,8);
      d += __shfl_xor(d,1); d += __shfl_xor(d,2); d += __shfl_xor(d,4); d += __shfl_xor(d,8);
      if (b == h && gr < N_){ asrc[gr*3+h] = s; adst[gr*3+h] = d; }
    }
  }
  // xw -> LDS bf16 -> coalesced global, 3 per-head planes
  #pragma unroll
  for (int nt = 0; nt < 12; ++nt){
    int col = nt*16 + b;
    #pragma unroll
    for (int r = 0; r < 4; ++r)
      sXW[(w*16 + q*4 + r)*196 + col] = f2bf(acc[nt][r]);
  }
  __syncthreads();
  #pragma unroll
  for (int i = 0; i < 4; ++i){
    int id = i*256 + t;                 // 1024 (row, c4) pairs
    int row = id >> 4, c4 = (id & 15)*4, gr = row0 + row;
    if (gr < N_){
      ushort4 v0 = *reinterpret_cast<ushort4*>(&sXW[row*196 + c4]);
      ushort4 v1 = *reinterpret_cast<ushort4*>(&sXW[row*196 + 64 + c4]);
      ushort4 v2 = *reinterpret_cast<ushort4*>(&sXW[row*196 + 128 + c4]);
      *reinterpret_cast<ushort4*>(xw + (size_t)gr*64 + c4) = v0;
      *reinterpret_cast<ushort4*>(xw + (size_t)N_*64 + (size_t)gr*64 + c4) = v1;
      *reinterpret_cast<ushort4*>(xw + (size_t)N_*128 + (size_t)gr*64 + c4) = v2;
    }
  }
}

// per-node attention + aggregation: one wave per node; att computed inline
// (wave-uniform: one v_exp per head per edge, no loop-carried chain).
__global__ __launch_bounds__(256) void k_agg(
    const int* __restrict__ row_ptr, const int* __restrict__ src_s,
    const float* __restrict__ el_s,
    const float* __restrict__ asrc, const float* __restrict__ adst,
    const unsigned short* __restrict__ xw,
    const float* __restrict__ bg,
    float* __restrict__ mbuf)
{
  const unsigned short* xw0 = xw;
  const unsigned short* xw1 = xw + (size_t)N_*64;
  const unsigned short* xw2 = xw + (size_t)N_*128;
  int n = blockIdx.x*4 + (threadIdx.x >> 6);
  int c = threadIdx.x & 63;
  if (n >= N_) return;
  int p0 = row_ptr[n], p1 = row_ptr[n+1];
  float ad0 = adst[n*3+0], ad1 = adst[n*3+1], ad2 = adst[n*3+2];
  float d0 = 0.f, d1 = 0.f, d2 = 0.f;
  float a0 = 0.f, a1 = 0.f, a2 = 0.f;
  int p = p0;
  for (; p + 4 <= p1; p += 4){
    int sv[4];
    #pragma unroll
    for (int u = 0; u < 4; ++u) sv[u] = src_s[p+u];
    unsigned short g0[4], g1[4], g2[4];
    #pragma unroll
    for (int u = 0; u < 4; ++u){
      size_t base = (size_t)sv[u]*64 + c;
      g0[u] = xw0[base]; g1[u] = xw1[base]; g2[u] = xw2[base];
    }
    #pragma unroll
    for (int u = 0; u < 4; ++u){
      float l0 = asrc[sv[u]*3+0] + ad0 + el_s[(p+u)*3+0];
      float l1 = asrc[sv[u]*3+1] + ad1 + el_s[(p+u)*3+1];
      float l2 = asrc[sv[u]*3+2] + ad2 + el_s[(p+u)*3+2];
      l0 = l0 > 0.f ? l0 : 0.2f*l0;
      l1 = l1 > 0.f ? l1 : 0.2f*l1;
      l2 = l2 > 0.f ? l2 : 0.2f*l2;
      float w0 = __expf(l0), w1 = __expf(l1), w2 = __expf(l2);
      d0 += w0; d1 += w1; d2 += w2;
      a0 = fmaf(w0, bf2f(g0[u]), a0);
      a1 = fmaf(w1, bf2f(g1[u]), a1);
      a2 = fmaf(w2, bf2f(g2[u]), a2);
    }
  }
  for (; p < p1; ++p){
    int s = src_s[p];
    size_t base = (size_t)s*64 + c;
    float l0 = asrc[s*3+0] + ad0 + el_s[p*3+0];
    float l1 = asrc[s*3+1] + ad1 + el_s[p*3+1];
    float l2 = asrc[s*3+2] + ad2 + el_s[p*3+2];
    l0 = l0 > 0.f ? l0 : 0.2f*l0;
    l1 = l1 > 0.f ? l1 : 0.2f*l1;
    l2 = l2 > 0.f ? l2 : 0.2f*l2;
    float w0 = __expf(l0), w1 = __expf(l1), w2 = __expf(l2);
    d0 += w0; d1 += w1; d2 += w2;
    a0 = fmaf(w0, bf2f(xw0[base]), a0);
    a1 = fmaf(w1, bf2f(xw1[base]), a1);
    a2 = fmaf(w2, bf2f(xw2[base]), a2);
  }
  float mp = (a0/(d0+1e-16f) + a1/(d1+1e-16f) + a2/(d2+1e-16f)) * (1.0f/3.0f) + bg[c];
  mbuf[(size_t)n*64 + c] = mp > 0.f ? mp : (__expf(mp) - 1.0f);  // celu
}

// GRU step via MFMA: gi = m@Wih^T, gh = h@Whh^T, gates, h update; BN stats.
__global__ __launch_bounds__(256) void k_gru(
    const float* __restrict__ mbuf, const float* __restrict__ hsrc,
    float* __restrict__ hbuf,
    const unsigned short* __restrict__ fI, const unsigned short* __restrict__ fH,
    const float* __restrict__ bih, const float* __restrict__ bhh,
    float* __restrict__ bn_stats)               // this step's slot (pre-zeroed)
{
  __shared__ short sMf[8*64*8];
  __shared__ short sHf[8*64*8];
  __shared__ float sH[64][68];
  __shared__ float sStat[128];
  const int t = threadIdx.x;
  const int row0 = blockIdx.x * 64;
  if (t < 128) sStat[t] = 0.f;
  {
    const int lr = t >> 4, k4 = (t & 15) * 4;
    const int kt = k4 >> 5, lanew = lr + (((k4>>3)&3)<<4), j0 = k4 & 7;
    #pragma unroll
    for (int i = 0; i < 4; ++i){
      int r = lr + i*16, gr = row0 + r;
      float4 vm = make_float4(0.f,0.f,0.f,0.f), vh = vm;
      if (gr < N_){ vm = ldg4(mbuf + (size_t)gr*64 + k4); vh = ldg4(hsrc + (size_t)gr*64 + k4); }
      ushort4 pm; pm.x=f2bf(vm.x); pm.y=f2bf(vm.y); pm.z=f2bf(vm.z); pm.w=f2bf(vm.w);
      ushort4 ph; ph.x=f2bf(vh.x); ph.y=f2bf(vh.y); ph.z=f2bf(vh.z); ph.w=f2bf(vh.w);
      *reinterpret_cast<ushort4*>(&sMf[((i*2+kt)*64 + lanew)*8 + j0]) = pm;
      *reinterpret_cast<ushort4*>(&sHf[((i*2+kt)*64 + lanew)*8 + j0]) = ph;
      sH[r][k4+0]=vh.x; sH[r][k4+1]=vh.y; sH[r][k4+2]=vh.z; sH[r][k4+3]=vh.w;
    }
  }
  __syncthreads();
  const int w = t >> 6, l = t & 63, q = l >> 4, b = l & 15;
  f32x4 aI[12], aH[12];
  #pragma unroll
  for (int nt = 0; nt < 12; ++nt){ aI[nt] = (f32x4){0.f,0.f,0.f,0.f}; aH[nt] = (f32x4){0.f,0.f,0.f,0.f}; }
  bf16x8 am0 = *reinterpret_cast<bf16x8*>(&sMf[((w*2+0)*64 + l)*8]);
  bf16x8 am1 = *reinterpret_cast<bf16x8*>(&sMf[((w*2+1)*64 + l)*8]);
  bf16x8 ah0 = *reinterpret_cast<bf16x8*>(&sHf[((w*2+0)*64 + l)*8]);
  bf16x8 ah1 = *reinterpret_cast<bf16x8*>(&sHf[((w*2+1)*64 + l)*8]);
  #pragma unroll
  for (int nt = 0; nt < 12; ++nt){
    bf16x8 bI0 = *reinterpret_cast<const bf16x8*>(fI + (size_t)((nt*2+0)*64 + l)*8);
    bf16x8 bI1 = *reinterpret_cast<const bf16x8*>(fI + (size_t)((nt*2+1)*64 + l)*8);
    bf16x8 bH0 = *reinterpret_cast<const bf16x8*>(fH + (size_t)((nt*2+0)*64 + l)*8);
    bf16x8 bH1 = *reinterpret_cast<const bf16x8*>(fH + (size_t)((nt*2+1)*64 + l)*8);
    aI[nt] = __builtin_amdgcn_mfma_f32_16x16x32_bf16(am0, bI0, aI[nt], 0, 0, 0);
    aI[nt] = __builtin_amdgcn_mfma_f32_16x16x32_bf16(am1, bI1, aI[nt], 0, 0, 0);
    aH[nt] = __builtin_amdgcn_mfma_f32_16x16x32_bf16(ah0, bH0, aH[nt], 0, 0, 0);
    aH[nt] = __builtin_amdgcn_mfma_f32_16x16x32_bf16(ah1, bH1, aH[nt], 0, 0, 0);
  }
  float s1[4] = {0.f,0.f,0.f,0.f}, s2[4] = {0.f,0.f,0.f,0.f};
  #pragma unroll
  for (int tt = 0; tt < 4; ++tt){
    int c = tt*16 + b;
    float bir = bih[c], biz = bih[64+c], bin = bih[128+c];
    float bhr = bhh[c], bhz = bhh[64+c], bhn = bhh[128+c];
    #pragma unroll
    for (int r = 0; r < 4; ++r){
      int row = w*16 + q*4 + r, gr = row0 + row;
      float rg = sigmoidf_(aI[tt][r]   + bir + aH[tt][r]   + bhr);
      float zg = sigmoidf_(aI[tt+4][r] + biz + aH[tt+4][r] + bhz);
      float ng = tanhf(aI[tt+8][r] + bin + rg*(aH[tt+8][r] + bhn));
      float ho = sH[row][c];
      float hv = (1.f - zg)*ng + zg*ho;
      if (gr < N_){
        hbuf[(size_t)gr*64 + c] = hv;
        s1[tt] += hv; s2[tt] += hv*hv;
      }
    }
  }
  #pragma unroll
  for (int tt = 0; tt < 4; ++tt){
    float v = s1[tt];
    v += __shfl_xor(v, 16); v += __shfl_xor(v, 32);
    float u = s2[tt];
    u += __shfl_xor(u, 16); u += __shfl_xor(u, 32);
    if (q == 0){
      atomicAdd(&sStat[tt*16 + b], v);
      atomicAdd(&sStat[64 + tt*16 + b], u);
    }
  }
  __syncthreads();
  if (t < 128) atomicAdd(&bn_stats[t], sStat[t]);
}

// out = [frag slots 0..5 | bn(hbuf)] @ Wlin + blin via MFMA
__global__ __launch_bounds__(256) void k_final(
    const unsigned short* __restrict__ ff, const float* __restrict__ hbuf,
    const float* __restrict__ bn_stats,     // slot 5
    const float* __restrict__ gamma, const float* __restrict__ beta,
    const unsigned short* __restrict__ fL, const float* __restrict__ blin,
    float* __restrict__ out)
{
  __shared__ short sAf[8*64*8];
  __shared__ float sSc[64], sSh[64];
  const int t = threadIdx.x;
  const int row0 = blockIdx.x * 64;
  if (t < 64){
    float mu  = bn_stats[t] * (1.0f/30000.0f);
    float var = bn_stats[64+t] * (1.0f/30000.0f) - mu*mu;
    float rs = rsqrtf(var + 1e-5f);
    float sc = gamma[5*64 + t] * rs;
    sSc[t] = sc;
    sSh[t] = beta[5*64 + t] - mu*sc;
  }
  __syncthreads();
  const int w = t >> 6, l = t & 63, q = l >> 4, b = l & 15;
  const int lr = t >> 4, k4 = (t & 15) * 4;
  const int kt = k4 >> 5, lanew = lr + (((k4>>3)&3)<<4), j0 = k4 & 7;
  // stage slot 6 = bn(hbuf)
  {
    #pragma unroll
    for (int i = 0; i < 4; ++i){
      int r = lr + i*16, gr = row0 + r;
      float4 v = make_float4(0.f,0.f,0.f,0.f);
      if (gr < N_){
        v = ldg4(hbuf + (size_t)gr*64 + k4);
        v.x = fmaf(v.x, sSc[k4+0], sSh[k4+0]);
        v.y = fmaf(v.y, sSc[k4+1], sSh[k4+1]);
        v.z = fmaf(v.z, sSc[k4+2], sSh[k4+2]);
        v.w = fmaf(v.w, sSc[k4+3], sSh[k4+3]);
      }
      ushort4 pk; pk.x=f2bf(v.x); pk.y=f2bf(v.y); pk.z=f2bf(v.z); pk.w=f2bf(v.w);
      *reinterpret_cast<ushort4*>(&sAf[((i*2+kt)*64 + lanew)*8 + j0]) = pk;
    }
  }
  __syncthreads();
  f32x4 acc[4];
  #pragma unroll
  for (int nt = 0; nt < 4; ++nt) acc[nt] = (f32x4){0.f,0.f,0.f,0.f};
  const unsigned short* fb = ff + (size_t)blockIdx.x*4096;
  #pragma unroll
  for (int kc = 0; kc < 6; ++kc){
    const unsigned short* fs = fb + (size_t)kc*GB_*4096;
    bf16x8 a0 = *reinterpret_cast<const bf16x8*>(fs + (w*2+0)*512 + l*8);
    bf16x8 a1 = *reinterpret_cast<const bf16x8*>(fs + (w*2+1)*512 + l*8);
    #pragma unroll
    for (int nt = 0; nt < 4; ++nt){
      bf16x8 b0 = *reinterpret_cast<const bf16x8*>(fL + (size_t)((nt*14 + kc*2+0)*64 + l)*8);
      bf16x8 b1 = *reinterpret_cast<const bf16x8*>(fL + (size_t)((nt*14 + kc*2+1)*64 + l)*8);
      acc[nt] = __builtin_amdgcn_mfma_f32_16x16x32_bf16(a0, b0, acc[nt], 0, 0, 0);
      acc[nt] = __builtin_amdgcn_mfma_f32_16x16x32_bf16(a1, b1, acc[nt], 0, 0, 0);
    }
  }
  {
    bf16x8 a0 = *reinterpret_cast<bf16x8*>(&sAf[((w*2+0)*64 + l)*8]);
    bf16x8 a1 = *reinterpret_cast<bf16x8*>(&sAf[((w*2+1)*64 + l)*8]);
    #pragma unroll
    for (int nt = 0; nt < 4; ++nt){
      bf16x8 b0 = *reinterpret_cast<const bf16x8*>(fL + (size_t)((nt*14 + 12)*64 + l)*8);
      bf16x8 b1 = *reinterpret_cast<const bf16x8*>(fL + (size_t)((nt*14 + 13)*64 + l)*8);
      acc[nt] = __builtin_amdgcn_mfma_f32_16x16x32_bf16(a0, b0, acc[nt], 0, 0, 0);
      acc[nt] = __builtin_amdgcn_mfma_f32_16x16x32_bf16(a1, b1, acc[nt], 0, 0, 0);
    }
  }
  #pragma unroll
  for (int nt = 0; nt < 4; ++nt){
    int col = nt*16 + b;
    float bl = blin[col];
    #pragma unroll
    for (int r = 0; r < 4; ++r){
      int gr = row0 + w*16 + q*4 + r;
      if (gr < N_) out[(size_t)gr*64 + col] = acc[nt][r] + bl;
    }
  }
}

// ---------------- launch ----------------

extern "C" void kernel_launch(void* const* d_in, const int* in_sizes, int n_in,
                              void* d_out, int out_size, void* d_ws, size_t ws_size,
                              hipStream_t stream) {
  const float* x        = (const float*)d_in[0];
  const int*   ei       = (const int*)  d_in[1];
  const float* edge_attr= (const float*)d_in[2];
  const float* Wg       = (const float*)d_in[3];
  const float* bg       = (const float*)d_in[4];
  const float* a_src    = (const float*)d_in[5];
  const float* a_dst    = (const float*)d_in[6];
  const float* We       = (const float*)d_in[7];
  const float* a_edge   = (const float*)d_in[8];
  const float* Wih      = (const float*)d_in[9];
  const float* Whh      = (const float*)d_in[10];
  const float* bih      = (const float*)d_in[11];
  const float* bhh      = (const float*)d_in[12];
  const float* gamma    = (const float*)d_in[13];
  const float* beta     = (const float*)d_in[14];
  const float* Wlin     = (const float*)d_in[15];
  const float* blin     = (const float*)d_in[16];
  float* out = (float*)d_out;

  char* w = (char*)d_ws;
  auto alloc = [&](size_t bytes) -> void* {
    void* p = (void*)w;
    w += (bytes + 255) & ~(size_t)255;
    return p;
  };
  int*   row_ptr = (int*)  alloc((size_t)(N_+1)*4);
  int*   deg     = (int*)  alloc((size_t)N_*4);
  int*   cursor  = (int*)  alloc((size_t)N_*4);
  int*   partial = (int*)  alloc(128*4);
  int*   src_s   = (int*)  alloc((size_t)E_*4);
  float* el_s    = (float*)alloc((size_t)E_*3*4);
  float* Pw      = (float*)alloc(48*4);
  unsigned short* fG = (unsigned short*)alloc(12288*2);
  unsigned short* fI = (unsigned short*)alloc(12288*2);
  unsigned short* fH = (unsigned short*)alloc(12288*2);
  unsigned short* fL = (unsigned short*)alloc(28672*2);
  unsigned short* xw = (unsigned short*)alloc((size_t)N_*192*2);   // 3 planes N*64
  unsigned short* ffrag = (unsigned short*)alloc((size_t)6*GB_*4096*2);
  float* asrc    = (float*)alloc((size_t)N_*3*4);
  float* adst    = (float*)alloc((size_t)N_*3*4);
  float* mbuf    = (float*)alloc((size_t)N_*64*4);
  float* hbuf    = (float*)alloc((size_t)N_*64*4);
  float* bn_stats= (float*)alloc(768*4);        // 6 slots of 128

  const int EB = (E_ + 255)/256;       // 1172

  k_wfrag  <<<258 + SCB, 256, 0, stream>>>(Wg, Wih, Whh, Wlin, We, a_edge,
                                           fG, fI, fH, fL, Pw, deg, bn_stats);
  k_hist   <<<EB, 256, 0, stream>>>(ei, deg);
  k_scanA  <<<SCB, 256, 0, stream>>>(deg, partial);
  k_scanB  <<<1, 128, 0, stream>>>(partial, row_ptr);
  k_scanC  <<<SCB, 256, 0, stream>>>(deg, partial, row_ptr, cursor);
  k_scatter<<<EB, 256, 0, stream>>>(ei, edge_attr, Pw, cursor, src_s, el_s);

  for (int step = 0; step < 6; ++step){
    const float* hsrc = (step == 0) ? x : hbuf;
    k_xw <<<GB_, 256, 0, stream>>>(hsrc,
                                   bn_stats + (size_t)(step > 0 ? step-1 : 0)*128,
                                   gamma, beta, step-1, step > 0 ? 1 : 0,
                                   fG, a_src, a_dst, xw, asrc, adst,
                                   ffrag + (size_t)step*GB_*4096);
    k_agg<<<(N_+3)/4, 256, 0, stream>>>(row_ptr, src_s, el_s, asrc, adst, xw, bg, mbuf);
    k_gru<<<GB_, 256, 0, stream>>>(mbuf, hsrc, hbuf, fI, fH, bih, bhh,
                                   bn_stats + (size_t)step*128);
  }
  k_final<<<GB_, 256, 0, stream>>>(ffrag, hbuf, bn_stats + 5*128,
                                   gamma, beta, fL, blin, out);
}

// Round 13
// 557.018 us; speedup vs baseline: 1.0354x; 1.0354x over previous
//
#include <hip/hip_runtime.h>
#include <math.h>

constexpr int N_ = 30000;
constexpr int E_ = 300000;
constexpr int SCB = (N_ + 255) / 256;   // 118 scan blocks
constexpr int GB_ = (N_ + 63) / 64;     // 469 GEMM blocks

using f32x4  = __attribute__((ext_vector_type(4))) float;
using bf16x8 = __attribute__((ext_vector_type(8))) short;

__device__ __forceinline__ float4 ldg4(const float* p){ return *reinterpret_cast<const float4*>(p); }

__device__ __forceinline__ unsigned short f2bf(float f){
  union { float f; unsigned int u; } v; v.f = f;
  unsigned int r = v.u + 0x7FFFu + ((v.u >> 16) & 1u);
  return (unsigned short)(r >> 16);
}
__device__ __forceinline__ float bf2f(unsigned short b){
  union { unsigned int u; float f; } v; v.u = ((unsigned int)b) << 16;
  return v.f;
}
__device__ __forceinline__ float sigmoidf_(float x){ return 1.0f/(1.0f + __expf(-x)); }

// ---------------- setup kernels (once per launch) ----------------

// blocks 0..255: bf16 B-fragment weights for MFMA 16x16x32
//   frag element (nt,kt,l,j) = B[k = kt*32 + (l>>4)*8 + j][n = nt*16 + (l&15)]
// block 256: P[j][h]; blocks 257..256+SCB: zero deg; block 257+SCB: zero bn_stats
__global__ void k_wfrag(const float* __restrict__ Wg, const float* __restrict__ Wih,
                        const float* __restrict__ Whh, const float* __restrict__ Wlin,
                        const float* __restrict__ We, const float* __restrict__ a_edge,
                        unsigned short* __restrict__ fG, unsigned short* __restrict__ fI,
                        unsigned short* __restrict__ fH, unsigned short* __restrict__ fL,
                        float* __restrict__ P, int* __restrict__ deg,
                        float* __restrict__ bn_stats){
  if (blockIdx.x == 257 + SCB){
    for (int k = threadIdx.x; k < 768; k += 256) bn_stats[k] = 0.f;
    return;
  }
  if (blockIdx.x >= 257){
    int i = (blockIdx.x - 257)*256 + threadIdx.x;
    if (i < N_) deg[i] = 0;
    return;
  }
  if (blockIdx.x == 256){
    int t = threadIdx.x; if (t >= 48) return;
    int j = t / 3, h = t % 3;
    float s = 0.f;
    for (int c = 0; c < 64; ++c) s += We[j*192 + h*64 + c] * a_edge[h*64 + c];
    P[j*3 + h] = s;
    return;
  }
  int id = blockIdx.x*256 + threadIdx.x;   // 0..65535
  int lid, KT;
  unsigned short* dst; int mode;
  if (id < 12288)      { lid = id;         KT = 2;  dst = fG; mode = 0; }
  else if (id < 24576) { lid = id - 12288; KT = 2;  dst = fI; mode = 1; }
  else if (id < 36864) { lid = id - 24576; KT = 2;  dst = fH; mode = 2; }
  else                 { lid = id - 36864; KT = 14; dst = fL; mode = 3; }
  int j = lid & 7, l = (lid >> 3) & 63, rest = lid >> 9;
  int kt = rest % KT, nt = rest / KT;
  int k = kt*32 + (l>>4)*8 + j;
  int n = nt*16 + (l&15);
  float v;
  if (mode == 0)      v = Wg[k*192 + n];
  else if (mode == 1) v = Wih[n*64 + k];
  else if (mode == 2) v = Whh[n*64 + k];
  else                v = Wlin[k*64 + n];
  dst[lid] = f2bf(v);
}

__global__ void k_hist(const int* __restrict__ ei, int* __restrict__ deg){
  int e = blockIdx.x*256 + threadIdx.x;
  if (e < E_) atomicAdd(&deg[ei[E_ + e]], 1);
}

__global__ void k_scanA(const int* __restrict__ deg, int* __restrict__ partial){
  int i = blockIdx.x*256 + threadIdx.x;
  int v = (i < N_) ? deg[i] : 0;
  #pragma unroll
  for (int off = 1; off < 64; off <<= 1) v += __shfl_xor(v, off);
  __shared__ int ws[4];
  if ((threadIdx.x & 63) == 0) ws[threadIdx.x >> 6] = v;
  __syncthreads();
  if (threadIdx.x == 0) partial[blockIdx.x] = ws[0] + ws[1] + ws[2] + ws[3];
}

__global__ void k_scanB(int* __restrict__ partial, int* __restrict__ row_ptr){
  __shared__ int s[128];
  int t = threadIdx.x;
  int v = (t < SCB) ? partial[t] : 0;
  s[t] = v; __syncthreads();
  for (int off = 1; off < 128; off <<= 1){
    int u = (t >= off) ? s[t-off] : 0;
    __syncthreads();
    s[t] += u;
    __syncthreads();
  }
  if (t < SCB) partial[t] = s[t] - v;   // exclusive
  if (t == 0) row_ptr[N_] = E_;
}

__global__ void k_scanC(const int* __restrict__ deg, const int* __restrict__ partial,
                        int* __restrict__ row_ptr, int* __restrict__ cursor){
  __shared__ int s[256];
  int t = threadIdx.x, i = blockIdx.x*256 + t;
  int v = (i < N_) ? deg[i] : 0;
  s[t] = v; __syncthreads();
  for (int off = 1; off < 256; off <<= 1){
    int u = (t >= off) ? s[t-off] : 0;
    __syncthreads();
    s[t] += u;
    __syncthreads();
  }
  int ex = s[t] - v + partial[blockIdx.x];
  if (i < N_){ row_ptr[i] = ex; cursor[i] = ex; }
}

// fused: edge logit term (edge_attr @ P) + CSR scatter (also records dst)
__global__ void k_scatter(const int* __restrict__ ei, const float* __restrict__ edge_attr,
                          const float* __restrict__ P,
                          int* __restrict__ cursor, int* __restrict__ src_s,
                          int* __restrict__ dst_s, float* __restrict__ el_s){
  __shared__ float sP[48];
  int t = threadIdx.x;
  if (t < 48) sP[t] = P[t];
  __syncthreads();
  int e = blockIdx.x*256 + t;
  if (e >= E_) return;
  const float* ea = edge_attr + (size_t)e*16;
  float v[16];
  #pragma unroll
  for (int q = 0; q < 4; ++q){
    float4 f = ldg4(ea + q*4);
    v[q*4+0]=f.x; v[q*4+1]=f.y; v[q*4+2]=f.z; v[q*4+3]=f.w;
  }
  float l0=0.f,l1=0.f,l2=0.f;
  #pragma unroll
  for (int j = 0; j < 16; ++j){
    l0 += v[j]*sP[j*3+0]; l1 += v[j]*sP[j*3+1]; l2 += v[j]*sP[j*3+2];
  }
  int d = ei[E_ + e];
  int p = atomicAdd(&cursor[d], 1);
  src_s[p] = ei[e];
  dst_s[p] = d;
  el_s[p*3+0] = l0; el_s[p*3+1] = l1; el_s[p*3+2] = l2;
}

// ---------------- per-step kernels ----------------

// fused BN(hsrc) + xw = bn(x)@Wg via MFMA + alpha dots; persists fragment
// tile for k_final; xw stored bf16 in 3 per-head planes [h][n][64].
__global__ __launch_bounds__(256) void k_xw(
    const float* __restrict__ hsrc,
    const float* __restrict__ bn_stats,     // slot of previous step
    const float* __restrict__ gamma, const float* __restrict__ beta,
    int gidx, int bn,
    const unsigned short* __restrict__ fG,
    const float* __restrict__ a_src, const float* __restrict__ a_dst,
    unsigned short* __restrict__ xw,        // 3 planes of N*64
    float* __restrict__ asrc, float* __restrict__ adst,
    unsigned short* __restrict__ fr)
{
  __shared__ short sAf[8*64*8];        // A-frag bf16, 8 KB
  __shared__ unsigned short sXW[64*196];
  __shared__ float sSc[64], sSh[64];
  const int t = threadIdx.x;
  const int row0 = blockIdx.x * 64;
  if (t < 64){
    float sc = 1.f, sh = 0.f;
    if (bn){
      float mu  = bn_stats[t] * (1.0f/30000.0f);
      float var = bn_stats[64+t] * (1.0f/30000.0f) - mu*mu;
      float rs = rsqrtf(var + 1e-5f);
      sc = gamma[gidx*64 + t] * rs;
      sh = beta[gidx*64 + t] - mu*sc;
    }
    sSc[t] = sc; sSh[t] = sh;
  }
  __syncthreads();
  {
    const int lr = t >> 4, k4 = (t & 15) * 4;
    const float sc0=sSc[k4],sc1=sSc[k4+1],sc2=sSc[k4+2],sc3=sSc[k4+3];
    const float sh0=sSh[k4],sh1=sSh[k4+1],sh2=sSh[k4+2],sh3=sSh[k4+3];
    const int kt = k4 >> 5, lanew = lr + (((k4>>3)&3)<<4), j0 = k4 & 7;
    #pragma unroll
    for (int i = 0; i < 4; ++i){
      int r = lr + i*16, gr = row0 + r;
      float4 v = make_float4(0.f,0.f,0.f,0.f);
      if (gr < N_){
        v = ldg4(hsrc + (size_t)gr*64 + k4);
        v.x = fmaf(v.x, sc0, sh0); v.y = fmaf(v.y, sc1, sh1);
        v.z = fmaf(v.z, sc2, sh2); v.w = fmaf(v.w, sc3, sh3);
      }
      ushort4 pk; pk.x=f2bf(v.x); pk.y=f2bf(v.y); pk.z=f2bf(v.z); pk.w=f2bf(v.w);
      *reinterpret_cast<ushort4*>(&sAf[((i*2+kt)*64 + lanew)*8 + j0]) = pk;
    }
  }
  __syncthreads();
  // persist the fragment tile for k_final
  {
    bf16x8 v0 = *reinterpret_cast<bf16x8*>(&sAf[t*8]);
    bf16x8 v1 = *reinterpret_cast<bf16x8*>(&sAf[2048 + t*8]);
    bf16x8* g = reinterpret_cast<bf16x8*>(fr + (size_t)blockIdx.x*4096);
    g[t] = v0; g[256 + t] = v1;
  }
  const int w = t >> 6, l = t & 63, q = l >> 4, b = l & 15;
  f32x4 acc[12];
  #pragma unroll
  for (int nt = 0; nt < 12; ++nt) acc[nt] = (f32x4){0.f,0.f,0.f,0.f};
  bf16x8 a0 = *reinterpret_cast<bf16x8*>(&sAf[((w*2+0)*64 + l)*8]);
  bf16x8 a1 = *reinterpret_cast<bf16x8*>(&sAf[((w*2+1)*64 + l)*8]);
  #pragma unroll
  for (int nt = 0; nt < 12; ++nt){
    bf16x8 b0 = *reinterpret_cast<const bf16x8*>(fG + (size_t)((nt*2+0)*64 + l)*8);
    bf16x8 b1 = *reinterpret_cast<const bf16x8*>(fG + (size_t)((nt*2+1)*64 + l)*8);
    acc[nt] = __builtin_amdgcn_mfma_f32_16x16x32_bf16(a0, b0, acc[nt], 0, 0, 0);
    acc[nt] = __builtin_amdgcn_mfma_f32_16x16x32_bf16(a1, b1, acc[nt], 0, 0, 0);
  }
  // attention dots
  float asl[3][4], adl[3][4];
  #pragma unroll
  for (int h = 0; h < 3; ++h)
    #pragma unroll
    for (int u = 0; u < 4; ++u){
      asl[h][u] = a_src[h*64 + u*16 + b];
      adl[h][u] = a_dst[h*64 + u*16 + b];
    }
  #pragma unroll
  for (int r = 0; r < 4; ++r){
    int gr = row0 + w*16 + q*4 + r;
    #pragma unroll
    for (int h = 0; h < 3; ++h){
      float s = 0.f, d = 0.f;
      #pragma unroll
      for (int u = 0; u < 4; ++u){
        s = fmaf(acc[4*h+u][r], asl[h][u], s);
        d = fmaf(acc[4*h+u][r], adl[h][u], d);
      }
      s += __shfl_xor(s,1); s += __shfl_xor(s,2); s += __shfl_xor(s,4); s += __shfl_xor(s,8);
      d += __shfl_xor(d,1); d += __shfl_xor(d,2); d += __shfl_xor(d,4); d += __shfl_xor(d,8);
      if (b == h && gr < N_){ asrc[gr*3+h] = s; adst[gr*3+h] = d; }
    }
  }
  // xw -> LDS bf16 -> coalesced global, 3 per-head planes
  #pragma unroll
  for (int nt = 0; nt < 12; ++nt){
    int col = nt*16 + b;
    #pragma unroll
    for (int r = 0; r < 4; ++r)
      sXW[(w*16 + q*4 + r)*196 + col] = f2bf(acc[nt][r]);
  }
  __syncthreads();
  #pragma unroll
  for (int i = 0; i < 4; ++i){
    int id = i*256 + t;                 // 1024 (row, c4) pairs
    int row = id >> 4, c4 = (id & 15)*4, gr = row0 + row;
    if (gr < N_){
      ushort4 v0 = *reinterpret_cast<ushort4*>(&sXW[row*196 + c4]);
      ushort4 v1 = *reinterpret_cast<ushort4*>(&sXW[row*196 + 64 + c4]);
      ushort4 v2 = *reinterpret_cast<ushort4*>(&sXW[row*196 + 128 + c4]);
      *reinterpret_cast<ushort4*>(xw + (size_t)gr*64 + c4) = v0;
      *reinterpret_cast<ushort4*>(xw + (size_t)N_*64 + (size_t)gr*64 + c4) = v1;
      *reinterpret_cast<ushort4*>(xw + (size_t)N_*128 + (size_t)gr*64 + c4) = v2;
    }
  }
}

// edge-parallel attention weights: att = exp(leaky_relu(asrc+adst+el))
// (no max-subtraction: algebraically identical softmax; logits are O(+-8))
__global__ void k_att(const int* __restrict__ src_s, const int* __restrict__ dst_s,
                      const float* __restrict__ el_s,
                      const float* __restrict__ asrc, const float* __restrict__ adst,
                      float* __restrict__ att_s){
  int p = blockIdx.x*256 + threadIdx.x;
  if (p >= E_) return;
  int s = src_s[p], d = dst_s[p];
  #pragma unroll
  for (int h = 0; h < 3; ++h){
    float l = asrc[s*3+h] + adst[d*3+h] + el_s[p*3+h];
    l = l > 0.f ? l : 0.2f*l;
    att_s[p*3+h] = __expf(l);
  }
}

// per-node weighted aggregation: one wave per node, three 2B plane-gathers
// per edge; writes m as bf16 (bit-identical: k_gru consumed m via f2bf anyway).
__global__ __launch_bounds__(256) void k_agg(
    const int* __restrict__ row_ptr, const int* __restrict__ src_s,
    const float* __restrict__ att_s,
    const unsigned short* __restrict__ xw,
    const float* __restrict__ bg,
    unsigned short* __restrict__ mbuf)
{
  const unsigned short* xw0 = xw;
  const unsigned short* xw1 = xw + (size_t)N_*64;
  const unsigned short* xw2 = xw + (size_t)N_*128;
  int n = blockIdx.x*4 + (threadIdx.x >> 6);
  int c = threadIdx.x & 63;
  if (n >= N_) return;
  int p0 = row_ptr[n], p1 = row_ptr[n+1];
  float d0 = 0.f, d1 = 0.f, d2 = 0.f;
  float a0 = 0.f, a1 = 0.f, a2 = 0.f;
  int p = p0;
  for (; p + 4 <= p1; p += 4){
    int sv[4];
    #pragma unroll
    for (int u = 0; u < 4; ++u) sv[u] = src_s[p+u];
    unsigned short g0[4], g1[4], g2[4];
    #pragma unroll
    for (int u = 0; u < 4; ++u){
      size_t base = (size_t)sv[u]*64 + c;
      g0[u] = xw0[base]; g1[u] = xw1[base]; g2[u] = xw2[base];
    }
    #pragma unroll
    for (int u = 0; u < 4; ++u){
      float w0 = att_s[(p+u)*3+0], w1 = att_s[(p+u)*3+1], w2 = att_s[(p+u)*3+2];
      d0 += w0; d1 += w1; d2 += w2;
      a0 = fmaf(w0, bf2f(g0[u]), a0);
      a1 = fmaf(w1, bf2f(g1[u]), a1);
      a2 = fmaf(w2, bf2f(g2[u]), a2);
    }
  }
  for (; p < p1; ++p){
    int s = src_s[p];
    size_t base = (size_t)s*64 + c;
    float w0 = att_s[p*3+0], w1 = att_s[p*3+1], w2 = att_s[p*3+2];
    d0 += w0; d1 += w1; d2 += w2;
    a0 = fmaf(w0, bf2f(xw0[base]), a0);
    a1 = fmaf(w1, bf2f(xw1[base]), a1);
    a2 = fmaf(w2, bf2f(xw2[base]), a2);
  }
  float mp = (a0/(d0+1e-16f) + a1/(d1+1e-16f) + a2/(d2+1e-16f)) * (1.0f/3.0f) + bg[c];
  mp = mp > 0.f ? mp : (__expf(mp) - 1.0f);   // celu
  mbuf[(size_t)n*64 + c] = f2bf(mp);
}

// GRU step via MFMA: gi = m@Wih^T, gh = h@Whh^T, gates, h update; BN stats.
// mbuf is bf16 (already fragment-ready values).
__global__ __launch_bounds__(256) void k_gru(
    const unsigned short* __restrict__ mbuf, const float* __restrict__ hsrc,
    float* __restrict__ hbuf,
    const unsigned short* __restrict__ fI, const unsigned short* __restrict__ fH,
    const float* __restrict__ bih, const float* __restrict__ bhh,
    float* __restrict__ bn_stats)               // this step's slot (pre-zeroed)
{
  __shared__ short sMf[8*64*8];
  __shared__ short sHf[8*64*8];
  __shared__ float sH[64][68];
  __shared__ float sStat[128];
  const int t = threadIdx.x;
  const int row0 = blockIdx.x * 64;
  if (t < 128) sStat[t] = 0.f;
  {
    const int lr = t >> 4, k4 = (t & 15) * 4;
    const int kt = k4 >> 5, lanew = lr + (((k4>>3)&3)<<4), j0 = k4 & 7;
    #pragma unroll
    for (int i = 0; i < 4; ++i){
      int r = lr + i*16, gr = row0 + r;
      ushort4 pm; pm.x = 0; pm.y = 0; pm.z = 0; pm.w = 0;
      float4 vh = make_float4(0.f,0.f,0.f,0.f);
      if (gr < N_){
        pm = *reinterpret_cast<const ushort4*>(mbuf + (size_t)gr*64 + k4);
        vh = ldg4(hsrc + (size_t)gr*64 + k4);
      }
      ushort4 ph; ph.x=f2bf(vh.x); ph.y=f2bf(vh.y); ph.z=f2bf(vh.z); ph.w=f2bf(vh.w);
      *reinterpret_cast<ushort4*>(&sMf[((i*2+kt)*64 + lanew)*8 + j0]) = pm;
      *reinterpret_cast<ushort4*>(&sHf[((i*2+kt)*64 + lanew)*8 + j0]) = ph;
      sH[r][k4+0]=vh.x; sH[r][k4+1]=vh.y; sH[r][k4+2]=vh.z; sH[r][k4+3]=vh.w;
    }
  }
  __syncthreads();
  const int w = t >> 6, l = t & 63, q = l >> 4, b = l & 15;
  f32x4 aI[12], aH[12];
  #pragma unroll
  for (int nt = 0; nt < 12; ++nt){ aI[nt] = (f32x4){0.f,0.f,0.f,0.f}; aH[nt] = (f32x4){0.f,0.f,0.f,0.f}; }
  bf16x8 am0 = *reinterpret_cast<bf16x8*>(&sMf[((w*2+0)*64 + l)*8]);
  bf16x8 am1 = *reinterpret_cast<bf16x8*>(&sMf[((w*2+1)*64 + l)*8]);
  bf16x8 ah0 = *reinterpret_cast<bf16x8*>(&sHf[((w*2+0)*64 + l)*8]);
  bf16x8 ah1 = *reinterpret_cast<bf16x8*>(&sHf[((w*2+1)*64 + l)*8]);
  #pragma unroll
  for (int nt = 0; nt < 12; ++nt){
    bf16x8 bI0 = *reinterpret_cast<const bf16x8*>(fI + (size_t)((nt*2+0)*64 + l)*8);
    bf16x8 bI1 = *reinterpret_cast<const bf16x8*>(fI + (size_t)((nt*2+1)*64 + l)*8);
    bf16x8 bH0 = *reinterpret_cast<const bf16x8*>(fH + (size_t)((nt*2+0)*64 + l)*8);
    bf16x8 bH1 = *reinterpret_cast<const bf16x8*>(fH + (size_t)((nt*2+1)*64 + l)*8);
    aI[nt] = __builtin_amdgcn_mfma_f32_16x16x32_bf16(am0, bI0, aI[nt], 0, 0, 0);
    aI[nt] = __builtin_amdgcn_mfma_f32_16x16x32_bf16(am1, bI1, aI[nt], 0, 0, 0);
    aH[nt] = __builtin_amdgcn_mfma_f32_16x16x32_bf16(ah0, bH0, aH[nt], 0, 0, 0);
    aH[nt] = __builtin_amdgcn_mfma_f32_16x16x32_bf16(ah1, bH1, aH[nt], 0, 0, 0);
  }
  float s1[4] = {0.f,0.f,0.f,0.f}, s2[4] = {0.f,0.f,0.f,0.f};
  #pragma unroll
  for (int tt = 0; tt < 4; ++tt){
    int c = tt*16 + b;
    float bir = bih[c], biz = bih[64+c], bin = bih[128+c];
    float bhr = bhh[c], bhz = bhh[64+c], bhn = bhh[128+c];
    #pragma unroll
    for (int r = 0; r < 4; ++r){
      int row = w*16 + q*4 + r, gr = row0 + row;
      float rg = sigmoidf_(aI[tt][r]   + bir + aH[tt][r]   + bhr);
      float zg = sigmoidf_(aI[tt+4][r] + biz + aH[tt+4][r] + bhz);
      float ng = tanhf(aI[tt+8][r] + bin + rg*(aH[tt+8][r] + bhn));
      float ho = sH[row][c];
      float hv = (1.f - zg)*ng + zg*ho;
      if (gr < N_){
        hbuf[(size_t)gr*64 + c] = hv;
        s1[tt] += hv; s2[tt] += hv*hv;
      }
    }
  }
  #pragma unroll
  for (int tt = 0; tt < 4; ++tt){
    float v = s1[tt];
    v += __shfl_xor(v, 16); v += __shfl_xor(v, 32);
    float u = s2[tt];
    u += __shfl_xor(u, 16); u += __shfl_xor(u, 32);
    if (q == 0){
      atomicAdd(&sStat[tt*16 + b], v);
      atomicAdd(&sStat[64 + tt*16 + b], u);
    }
  }
  __syncthreads();
  if (t < 128) atomicAdd(&bn_stats[t], sStat[t]);
}

// out = [frag slots 0..5 | bn(hbuf)] @ Wlin + blin via MFMA
__global__ __launch_bounds__(256) void k_final(
    const unsigned short* __restrict__ ff, const float* __restrict__ hbuf,
    const float* __restrict__ bn_stats,     // slot 5
    const float* __restrict__ gamma, const float* __restrict__ beta,
    const unsigned short* __restrict__ fL, const float* __restrict__ blin,
    float* __restrict__ out)
{
  __shared__ short sAf[8*64*8];
  __shared__ float sSc[64], sSh[64];
  const int t = threadIdx.x;
  const int row0 = blockIdx.x * 64;
  if (t < 64){
    float mu  = bn_stats[t] * (1.0f/30000.0f);
    float var = bn_stats[64+t] * (1.0f/30000.0f) - mu*mu;
    float rs = rsqrtf(var + 1e-5f);
    float sc = gamma[5*64 + t] * rs;
    sSc[t] = sc;
    sSh[t] = beta[5*64 + t] - mu*sc;
  }
  __syncthreads();
  const int w = t >> 6, l = t & 63, q = l >> 4, b = l & 15;
  const int lr = t >> 4, k4 = (t & 15) * 4;
  const int kt = k4 >> 5, lanew = lr + (((k4>>3)&3)<<4), j0 = k4 & 7;
  // stage slot 6 = bn(hbuf)
  {
    #pragma unroll
    for (int i = 0; i < 4; ++i){
      int r = lr + i*16, gr = row0 + r;
      float4 v = make_float4(0.f,0.f,0.f,0.f);
      if (gr < N_){
        v = ldg4(hbuf + (size_t)gr*64 + k4);
        v.x = fmaf(v.x, sSc[k4+0], sSh[k4+0]);
        v.y = fmaf(v.y, sSc[k4+1], sSh[k4+1]);
        v.z = fmaf(v.z, sSc[k4+2], sSh[k4+2]);
        v.w = fmaf(v.w, sSc[k4+3], sSh[k4+3]);
      }
      ushort4 pk; pk.x=f2bf(v.x); pk.y=f2bf(v.y); pk.z=f2bf(v.z); pk.w=f2bf(v.w);
      *reinterpret_cast<ushort4*>(&sAf[((i*2+kt)*64 + lanew)*8 + j0]) = pk;
    }
  }
  __syncthreads();
  f32x4 acc[4];
  #pragma unroll
  for (int nt = 0; nt < 4; ++nt) acc[nt] = (f32x4){0.f,0.f,0.f,0.f};
  const unsigned short* fb = ff + (size_t)blockIdx.x*4096;
  #pragma unroll
  for (int kc = 0; kc < 6; ++kc){
    const unsigned short* fs = fb + (size_t)kc*GB_*4096;
    bf16x8 a0 = *reinterpret_cast<const bf16x8*>(fs + (w*2+0)*512 + l*8);
    bf16x8 a1 = *reinterpret_cast<const bf16x8*>(fs + (w*2+1)*512 + l*8);
    #pragma unroll
    for (int nt = 0; nt < 4; ++nt){
      bf16x8 b0 = *reinterpret_cast<const bf16x8*>(fL + (size_t)((nt*14 + kc*2+0)*64 + l)*8);
      bf16x8 b1 = *reinterpret_cast<const bf16x8*>(fL + (size_t)((nt*14 + kc*2+1)*64 + l)*8);
      acc[nt] = __builtin_amdgcn_mfma_f32_16x16x32_bf16(a0, b0, acc[nt], 0, 0, 0);
      acc[nt] = __builtin_amdgcn_mfma_f32_16x16x32_bf16(a1, b1, acc[nt], 0, 0, 0);
    }
  }
  {
    bf16x8 a0 = *reinterpret_cast<bf16x8*>(&sAf[((w*2+0)*64 + l)*8]);
    bf16x8 a1 = *reinterpret_cast<bf16x8*>(&sAf[((w*2+1)*64 + l)*8]);
    #pragma unroll
    for (int nt = 0; nt < 4; ++nt){
      bf16x8 b0 = *reinterpret_cast<const bf16x8*>(fL + (size_t)((nt*14 + 12)*64 + l)*8);
      bf16x8 b1 = *reinterpret_cast<const bf16x8*>(fL + (size_t)((nt*14 + 13)*64 + l)*8);
      acc[nt] = __builtin_amdgcn_mfma_f32_16x16x32_bf16(a0, b0, acc[nt], 0, 0, 0);
      acc[nt] = __builtin_amdgcn_mfma_f32_16x16x32_bf16(a1, b1, acc[nt], 0, 0, 0);
    }
  }
  #pragma unroll
  for (int nt = 0; nt < 4; ++nt){
    int col = nt*16 + b;
    float bl = blin[col];
    #pragma unroll
    for (int r = 0; r < 4; ++r){
      int gr = row0 + w*16 + q*4 + r;
      if (gr < N_) out[(size_t)gr*64 + col] = acc[nt][r] + bl;
    }
  }
}

// ---------------- launch ----------------

extern "C" void kernel_launch(void* const* d_in, const int* in_sizes, int n_in,
                              void* d_out, int out_size, void* d_ws, size_t ws_size,
                              hipStream_t stream) {
  const float* x        = (const float*)d_in[0];
  const int*   ei       = (const int*)  d_in[1];
  const float* edge_attr= (const float*)d_in[2];
  const float* Wg       = (const float*)d_in[3];
  const float* bg       = (const float*)d_in[4];
  const float* a_src    = (const float*)d_in[5];
  const float* a_dst    = (const float*)d_in[6];
  const float* We       = (const float*)d_in[7];
  const float* a_edge   = (const float*)d_in[8];
  const float* Wih      = (const float*)d_in[9];
  const float* Whh      = (const float*)d_in[10];
  const float* bih      = (const float*)d_in[11];
  const float* bhh      = (const float*)d_in[12];
  const float* gamma    = (const float*)d_in[13];
  const float* beta     = (const float*)d_in[14];
  const float* Wlin     = (const float*)d_in[15];
  const float* blin     = (const float*)d_in[16];
  float* out = (float*)d_out;

  char* w = (char*)d_ws;
  auto alloc = [&](size_t bytes) -> void* {
    void* p = (void*)w;
    w += (bytes + 255) & ~(size_t)255;
    return p;
  };
  int*   row_ptr = (int*)  alloc((size_t)(N_+1)*4);
  int*   deg     = (int*)  alloc((size_t)N_*4);
  int*   cursor  = (int*)  alloc((size_t)N_*4);
  int*   partial = (int*)  alloc(128*4);
  int*   src_s   = (int*)  alloc((size_t)E_*4);
  int*   dst_s   = (int*)  alloc((size_t)E_*4);
  float* el_s    = (float*)alloc((size_t)E_*3*4);
  float* att_s   = (float*)alloc((size_t)E_*3*4);
  float* Pw      = (float*)alloc(48*4);
  unsigned short* fG = (unsigned short*)alloc(12288*2);
  unsigned short* fI = (unsigned short*)alloc(12288*2);
  unsigned short* fH = (unsigned short*)alloc(12288*2);
  unsigned short* fL = (unsigned short*)alloc(28672*2);
  unsigned short* xw = (unsigned short*)alloc((size_t)N_*192*2);   // 3 planes N*64
  unsigned short* ffrag = (unsigned short*)alloc((size_t)6*GB_*4096*2);
  float* asrc    = (float*)alloc((size_t)N_*3*4);
  float* adst    = (float*)alloc((size_t)N_*3*4);
  unsigned short* mbuf = (unsigned short*)alloc((size_t)N_*64*2);
  float* hbuf    = (float*)alloc((size_t)N_*64*4);
  float* bn_stats= (float*)alloc(768*4);        // 6 slots of 128

  const int EB = (E_ + 255)/256;       // 1172

  k_wfrag  <<<258 + SCB, 256, 0, stream>>>(Wg, Wih, Whh, Wlin, We, a_edge,
                                           fG, fI, fH, fL, Pw, deg, bn_stats);
  k_hist   <<<EB, 256, 0, stream>>>(ei, deg);
  k_scanA  <<<SCB, 256, 0, stream>>>(deg, partial);
  k_scanB  <<<1, 128, 0, stream>>>(partial, row_ptr);
  k_scanC  <<<SCB, 256, 0, stream>>>(deg, partial, row_ptr, cursor);
  k_scatter<<<EB, 256, 0, stream>>>(ei, edge_attr, Pw, cursor, src_s, dst_s, el_s);

  for (int step = 0; step < 6; ++step){
    const float* hsrc = (step == 0) ? x : hbuf;
    k_xw <<<GB_, 256, 0, stream>>>(hsrc,
                                   bn_stats + (size_t)(step > 0 ? step-1 : 0)*128,
                                   gamma, beta, step-1, step > 0 ? 1 : 0,
                                   fG, a_src, a_dst, xw, asrc, adst,
                                   ffrag + (size_t)step*GB_*4096);
    k_att<<<EB, 256, 0, stream>>>(src_s, dst_s, el_s, asrc, adst, att_s);
    k_agg<<<(N_+3)/4, 256, 0, stream>>>(row_ptr, src_s, att_s, xw, bg, mbuf);
    k_gru<<<GB_, 256, 0, stream>>>(mbuf, hsrc, hbuf, fI, fH, bih, bhh,
                                   bn_stats + (size_t)step*128);
  }
  k_final<<<GB_, 256, 0, stream>>>(ffrag, hbuf, bn_stats + 5*128,
                                   gamma, beta, fL, blin, out);
}

// Round 14
// 551.674 us; speedup vs baseline: 1.0455x; 1.0097x over previous
//
#include <hip/hip_runtime.h>
#include <math.h>

constexpr int N_ = 30000;
constexpr int E_ = 300000;
constexpr int SCB = (N_ + 255) / 256;   // 118 scan blocks
constexpr int GB_ = (N_ + 63) / 64;     // 469 GEMM blocks

using f32x4  = __attribute__((ext_vector_type(4))) float;
using bf16x8 = __attribute__((ext_vector_type(8))) short;

__device__ __forceinline__ float4 ldg4(const float* p){ return *reinterpret_cast<const float4*>(p); }

__device__ __forceinline__ unsigned short f2bf(float f){
  union { float f; unsigned int u; } v; v.f = f;
  unsigned int r = v.u + 0x7FFFu + ((v.u >> 16) & 1u);
  return (unsigned short)(r >> 16);
}
__device__ __forceinline__ float bf2f(unsigned short b){
  union { unsigned int u; float f; } v; v.u = ((unsigned int)b) << 16;
  return v.f;
}
__device__ __forceinline__ float sigmoidf_(float x){ return 1.0f/(1.0f + __expf(-x)); }

// ---------------- setup kernels (once per launch) ----------------

// blocks 0..255: bf16 B-fragment weights for MFMA 16x16x32
//   frag element (nt,kt,l,j) = B[k = kt*32 + (l>>4)*8 + j][n = nt*16 + (l&15)]
// block 256: P[j][h]; blocks 257..256+SCB: zero deg; block 257+SCB: zero bn_stats
__global__ void k_wfrag(const float* __restrict__ Wg, const float* __restrict__ Wih,
                        const float* __restrict__ Whh, const float* __restrict__ Wlin,
                        const float* __restrict__ We, const float* __restrict__ a_edge,
                        unsigned short* __restrict__ fG, unsigned short* __restrict__ fI,
                        unsigned short* __restrict__ fH, unsigned short* __restrict__ fL,
                        float* __restrict__ P, int* __restrict__ deg,
                        float* __restrict__ bn_stats){
  if (blockIdx.x == 257 + SCB){
    for (int k = threadIdx.x; k < 768; k += 256) bn_stats[k] = 0.f;
    return;
  }
  if (blockIdx.x >= 257){
    int i = (blockIdx.x - 257)*256 + threadIdx.x;
    if (i < N_) deg[i] = 0;
    return;
  }
  if (blockIdx.x == 256){
    int t = threadIdx.x; if (t >= 48) return;
    int j = t / 3, h = t % 3;
    float s = 0.f;
    for (int c = 0; c < 64; ++c) s += We[j*192 + h*64 + c] * a_edge[h*64 + c];
    P[j*3 + h] = s;
    return;
  }
  int id = blockIdx.x*256 + threadIdx.x;   // 0..65535
  int lid, KT;
  unsigned short* dst; int mode;
  if (id < 12288)      { lid = id;         KT = 2;  dst = fG; mode = 0; }
  else if (id < 24576) { lid = id - 12288; KT = 2;  dst = fI; mode = 1; }
  else if (id < 36864) { lid = id - 24576; KT = 2;  dst = fH; mode = 2; }
  else                 { lid = id - 36864; KT = 14; dst = fL; mode = 3; }
  int j = lid & 7, l = (lid >> 3) & 63, rest = lid >> 9;
  int kt = rest % KT, nt = rest / KT;
  int k = kt*32 + (l>>4)*8 + j;
  int n = nt*16 + (l&15);
  float v;
  if (mode == 0)      v = Wg[k*192 + n];
  else if (mode == 1) v = Wih[n*64 + k];
  else if (mode == 2) v = Whh[n*64 + k];
  else                v = Wlin[k*64 + n];
  dst[lid] = f2bf(v);
}

__global__ void k_hist(const int* __restrict__ ei, int* __restrict__ deg){
  int e = blockIdx.x*256 + threadIdx.x;
  if (e < E_) atomicAdd(&deg[ei[E_ + e]], 1);
}

__global__ void k_scanA(const int* __restrict__ deg, int* __restrict__ partial){
  int i = blockIdx.x*256 + threadIdx.x;
  int v = (i < N_) ? deg[i] : 0;
  #pragma unroll
  for (int off = 1; off < 64; off <<= 1) v += __shfl_xor(v, off);
  __shared__ int ws[4];
  if ((threadIdx.x & 63) == 0) ws[threadIdx.x >> 6] = v;
  __syncthreads();
  if (threadIdx.x == 0) partial[blockIdx.x] = ws[0] + ws[1] + ws[2] + ws[3];
}

__global__ void k_scanB(int* __restrict__ partial, int* __restrict__ row_ptr){
  __shared__ int s[128];
  int t = threadIdx.x;
  int v = (t < SCB) ? partial[t] : 0;
  s[t] = v; __syncthreads();
  for (int off = 1; off < 128; off <<= 1){
    int u = (t >= off) ? s[t-off] : 0;
    __syncthreads();
    s[t] += u;
    __syncthreads();
  }
  if (t < SCB) partial[t] = s[t] - v;   // exclusive
  if (t == 0) row_ptr[N_] = E_;
}

__global__ void k_scanC(const int* __restrict__ deg, const int* __restrict__ partial,
                        int* __restrict__ row_ptr, int* __restrict__ cursor){
  __shared__ int s[256];
  int t = threadIdx.x, i = blockIdx.x*256 + t;
  int v = (i < N_) ? deg[i] : 0;
  s[t] = v; __syncthreads();
  for (int off = 1; off < 256; off <<= 1){
    int u = (t >= off) ? s[t-off] : 0;
    __syncthreads();
    s[t] += u;
    __syncthreads();
  }
  int ex = s[t] - v + partial[blockIdx.x];
  if (i < N_){ row_ptr[i] = ex; cursor[i] = ex; }
}

// fused: edge logit term (edge_attr @ P) + CSR scatter (also records dst)
__global__ void k_scatter(const int* __restrict__ ei, const float* __restrict__ edge_attr,
                          const float* __restrict__ P,
                          int* __restrict__ cursor, int* __restrict__ src_s,
                          int* __restrict__ dst_s, float* __restrict__ el_s){
  __shared__ float sP[48];
  int t = threadIdx.x;
  if (t < 48) sP[t] = P[t];
  __syncthreads();
  int e = blockIdx.x*256 + t;
  if (e >= E_) return;
  const float* ea = edge_attr + (size_t)e*16;
  float v[16];
  #pragma unroll
  for (int q = 0; q < 4; ++q){
    float4 f = ldg4(ea + q*4);
    v[q*4+0]=f.x; v[q*4+1]=f.y; v[q*4+2]=f.z; v[q*4+3]=f.w;
  }
  float l0=0.f,l1=0.f,l2=0.f;
  #pragma unroll
  for (int j = 0; j < 16; ++j){
    l0 += v[j]*sP[j*3+0]; l1 += v[j]*sP[j*3+1]; l2 += v[j]*sP[j*3+2];
  }
  int d = ei[E_ + e];
  int p = atomicAdd(&cursor[d], 1);
  src_s[p] = ei[e];
  dst_s[p] = d;
  el_s[p*3+0] = l0; el_s[p*3+1] = l1; el_s[p*3+2] = l2;
}

// ---------------- per-step kernels ----------------

// fused BN(hsrc) + xw = bn(x)@Wg via MFMA + alpha dots; persists fragment
// tile for k_final; xw stored bf16 in 3 per-head planes [h][n][64].
__global__ __launch_bounds__(256) void k_xw(
    const float* __restrict__ hsrc,
    const float* __restrict__ bn_stats,     // slot of previous step
    const float* __restrict__ gamma, const float* __restrict__ beta,
    int gidx, int bn,
    const unsigned short* __restrict__ fG,
    const float* __restrict__ a_src, const float* __restrict__ a_dst,
    unsigned short* __restrict__ xw,        // 3 planes of N*64
    float* __restrict__ asrc, float* __restrict__ adst,
    unsigned short* __restrict__ fr)
{
  __shared__ short sAf[8*64*8];        // A-frag bf16, 8 KB
  __shared__ unsigned short sXW[64*196];
  __shared__ float sSc[64], sSh[64];
  const int t = threadIdx.x;
  const int row0 = blockIdx.x * 64;
  if (t < 64){
    float sc = 1.f, sh = 0.f;
    if (bn){
      float mu  = bn_stats[t] * (1.0f/30000.0f);
      float var = bn_stats[64+t] * (1.0f/30000.0f) - mu*mu;
      float rs = rsqrtf(var + 1e-5f);
      sc = gamma[gidx*64 + t] * rs;
      sh = beta[gidx*64 + t] - mu*sc;
    }
    sSc[t] = sc; sSh[t] = sh;
  }
  __syncthreads();
  {
    const int lr = t >> 4, k4 = (t & 15) * 4;
    const float sc0=sSc[k4],sc1=sSc[k4+1],sc2=sSc[k4+2],sc3=sSc[k4+3];
    const float sh0=sSh[k4],sh1=sSh[k4+1],sh2=sSh[k4+2],sh3=sSh[k4+3];
    const int kt = k4 >> 5, lanew = lr + (((k4>>3)&3)<<4), j0 = k4 & 7;
    #pragma unroll
    for (int i = 0; i < 4; ++i){
      int r = lr + i*16, gr = row0 + r;
      float4 v = make_float4(0.f,0.f,0.f,0.f);
      if (gr < N_){
        v = ldg4(hsrc + (size_t)gr*64 + k4);
        v.x = fmaf(v.x, sc0, sh0); v.y = fmaf(v.y, sc1, sh1);
        v.z = fmaf(v.z, sc2, sh2); v.w = fmaf(v.w, sc3, sh3);
      }
      ushort4 pk; pk.x=f2bf(v.x); pk.y=f2bf(v.y); pk.z=f2bf(v.z); pk.w=f2bf(v.w);
      *reinterpret_cast<ushort4*>(&sAf[((i*2+kt)*64 + lanew)*8 + j0]) = pk;
    }
  }
  __syncthreads();
  // persist the fragment tile for k_final
  {
    bf16x8 v0 = *reinterpret_cast<bf16x8*>(&sAf[t*8]);
    bf16x8 v1 = *reinterpret_cast<bf16x8*>(&sAf[2048 + t*8]);
    bf16x8* g = reinterpret_cast<bf16x8*>(fr + (size_t)blockIdx.x*4096);
    g[t] = v0; g[256 + t] = v1;
  }
  const int w = t >> 6, l = t & 63, q = l >> 4, b = l & 15;
  f32x4 acc[12];
  #pragma unroll
  for (int nt = 0; nt < 12; ++nt) acc[nt] = (f32x4){0.f,0.f,0.f,0.f};
  bf16x8 a0 = *reinterpret_cast<bf16x8*>(&sAf[((w*2+0)*64 + l)*8]);
  bf16x8 a1 = *reinterpret_cast<bf16x8*>(&sAf[((w*2+1)*64 + l)*8]);
  #pragma unroll
  for (int nt = 0; nt < 12; ++nt){
    bf16x8 b0 = *reinterpret_cast<const bf16x8*>(fG + (size_t)((nt*2+0)*64 + l)*8);
    bf16x8 b1 = *reinterpret_cast<const bf16x8*>(fG + (size_t)((nt*2+1)*64 + l)*8);
    acc[nt] = __builtin_amdgcn_mfma_f32_16x16x32_bf16(a0, b0, acc[nt], 0, 0, 0);
    acc[nt] = __builtin_amdgcn_mfma_f32_16x16x32_bf16(a1, b1, acc[nt], 0, 0, 0);
  }
  // attention dots
  float asl[3][4], adl[3][4];
  #pragma unroll
  for (int h = 0; h < 3; ++h)
    #pragma unroll
    for (int u = 0; u < 4; ++u){
      asl[h][u] = a_src[h*64 + u*16 + b];
      adl[h][u] = a_dst[h*64 + u*16 + b];
    }
  #pragma unroll
  for (int r = 0; r < 4; ++r){
    int gr = row0 + w*16 + q*4 + r;
    #pragma unroll
    for (int h = 0; h < 3; ++h){
      float s = 0.f, d = 0.f;
      #pragma unroll
      for (int u = 0; u < 4; ++u){
        s = fmaf(acc[4*h+u][r], asl[h][u], s);
        d = fmaf(acc[4*h+u][r], adl[h][u], d);
      }
      s += __shfl_xor(s,1); s += __shfl_xor(s,2); s += __shfl_xor(s,4); s += __shfl_xor(s,8);
      d += __shfl_xor(d,1); d += __shfl_xor(d,2); d += __shfl_xor(d,4); d += __shfl_xor(d,8);
      if (b == h && gr < N_){ asrc[gr*3+h] = s; adst[gr*3+h] = d; }
    }
  }
  // xw -> LDS bf16 -> coalesced global, 3 per-head planes
  #pragma unroll
  for (int nt = 0; nt < 12; ++nt){
    int col = nt*16 + b;
    #pragma unroll
    for (int r = 0; r < 4; ++r)
      sXW[(w*16 + q*4 + r)*196 + col] = f2bf(acc[nt][r]);
  }
  __syncthreads();
  #pragma unroll
  for (int i = 0; i < 4; ++i){
    int id = i*256 + t;                 // 1024 (row, c4) pairs
    int row = id >> 4, c4 = (id & 15)*4, gr = row0 + row;
    if (gr < N_){
      ushort4 v0 = *reinterpret_cast<ushort4*>(&sXW[row*196 + c4]);
      ushort4 v1 = *reinterpret_cast<ushort4*>(&sXW[row*196 + 64 + c4]);
      ushort4 v2 = *reinterpret_cast<ushort4*>(&sXW[row*196 + 128 + c4]);
      *reinterpret_cast<ushort4*>(xw + (size_t)gr*64 + c4) = v0;
      *reinterpret_cast<ushort4*>(xw + (size_t)N_*64 + (size_t)gr*64 + c4) = v1;
      *reinterpret_cast<ushort4*>(xw + (size_t)N_*128 + (size_t)gr*64 + c4) = v2;
    }
  }
}

// edge-parallel attention weights: att = exp(leaky_relu(asrc+adst+el))
// (no max-subtraction: algebraically identical softmax; logits are O(+-8))
__global__ void k_att(const int* __restrict__ src_s, const int* __restrict__ dst_s,
                      const float* __restrict__ el_s,
                      const float* __restrict__ asrc, const float* __restrict__ adst,
                      float* __restrict__ att_s){
  int p = blockIdx.x*256 + threadIdx.x;
  if (p >= E_) return;
  int s = src_s[p], d = dst_s[p];
  #pragma unroll
  for (int h = 0; h < 3; ++h){
    float l = asrc[s*3+h] + adst[d*3+h] + el_s[p*3+h];
    l = l > 0.f ? l : 0.2f*l;
    att_s[p*3+h] = __expf(l);
  }
}

// per-node weighted aggregation: one wave per node, three 2B plane-gathers
// per edge, 8-edge unroll for deep MLP; writes m as bf16.
__global__ __launch_bounds__(256) void k_agg(
    const int* __restrict__ row_ptr, const int* __restrict__ src_s,
    const float* __restrict__ att_s,
    const unsigned short* __restrict__ xw,
    const float* __restrict__ bg,
    unsigned short* __restrict__ mbuf)
{
  const unsigned short* xw0 = xw;
  const unsigned short* xw1 = xw + (size_t)N_*64;
  const unsigned short* xw2 = xw + (size_t)N_*128;
  int n = blockIdx.x*4 + (threadIdx.x >> 6);
  int c = threadIdx.x & 63;
  if (n >= N_) return;
  int p0 = row_ptr[n], p1 = row_ptr[n+1];
  float d0 = 0.f, d1 = 0.f, d2 = 0.f;
  float a0 = 0.f, a1 = 0.f, a2 = 0.f;
  int p = p0;
  for (; p + 8 <= p1; p += 8){
    int sv[8];
    #pragma unroll
    for (int u = 0; u < 8; ++u) sv[u] = src_s[p+u];
    unsigned short g0[8], g1[8], g2[8];
    #pragma unroll
    for (int u = 0; u < 8; ++u){
      size_t base = (size_t)sv[u]*64 + c;
      g0[u] = xw0[base]; g1[u] = xw1[base]; g2[u] = xw2[base];
    }
    float at[8][3];
    #pragma unroll
    for (int u = 0; u < 8; ++u){
      at[u][0] = att_s[(p+u)*3+0];
      at[u][1] = att_s[(p+u)*3+1];
      at[u][2] = att_s[(p+u)*3+2];
    }
    #pragma unroll
    for (int u = 0; u < 8; ++u){
      d0 += at[u][0]; d1 += at[u][1]; d2 += at[u][2];
      a0 = fmaf(at[u][0], bf2f(g0[u]), a0);
      a1 = fmaf(at[u][1], bf2f(g1[u]), a1);
      a2 = fmaf(at[u][2], bf2f(g2[u]), a2);
    }
  }
  for (; p + 4 <= p1; p += 4){
    int sv[4];
    #pragma unroll
    for (int u = 0; u < 4; ++u) sv[u] = src_s[p+u];
    unsigned short g0[4], g1[4], g2[4];
    #pragma unroll
    for (int u = 0; u < 4; ++u){
      size_t base = (size_t)sv[u]*64 + c;
      g0[u] = xw0[base]; g1[u] = xw1[base]; g2[u] = xw2[base];
    }
    #pragma unroll
    for (int u = 0; u < 4; ++u){
      float w0 = att_s[(p+u)*3+0], w1 = att_s[(p+u)*3+1], w2 = att_s[(p+u)*3+2];
      d0 += w0; d1 += w1; d2 += w2;
      a0 = fmaf(w0, bf2f(g0[u]), a0);
      a1 = fmaf(w1, bf2f(g1[u]), a1);
      a2 = fmaf(w2, bf2f(g2[u]), a2);
    }
  }
  for (; p < p1; ++p){
    int s = src_s[p];
    size_t base = (size_t)s*64 + c;
    float w0 = att_s[p*3+0], w1 = att_s[p*3+1], w2 = att_s[p*3+2];
    d0 += w0; d1 += w1; d2 += w2;
    a0 = fmaf(w0, bf2f(xw0[base]), a0);
    a1 = fmaf(w1, bf2f(xw1[base]), a1);
    a2 = fmaf(w2, bf2f(xw2[base]), a2);
  }
  float mp = (a0/(d0+1e-16f) + a1/(d1+1e-16f) + a2/(d2+1e-16f)) * (1.0f/3.0f) + bg[c];
  mp = mp > 0.f ? mp : (__expf(mp) - 1.0f);   // celu
  mbuf[(size_t)n*64 + c] = f2bf(mp);
}

// GRU step via MFMA: gi = m@Wih^T, gh = h@Whh^T, gates, h update; BN stats.
// mbuf is bf16 (already fragment-ready values).
__global__ __launch_bounds__(256) void k_gru(
    const unsigned short* __restrict__ mbuf, const float* __restrict__ hsrc,
    float* __restrict__ hbuf,
    const unsigned short* __restrict__ fI, const unsigned short* __restrict__ fH,
    const float* __restrict__ bih, const float* __restrict__ bhh,
    float* __restrict__ bn_stats)               // this step's slot (pre-zeroed)
{
  __shared__ short sMf[8*64*8];
  __shared__ short sHf[8*64*8];
  __shared__ float sH[64][68];
  __shared__ float sStat[128];
  const int t = threadIdx.x;
  const int row0 = blockIdx.x * 64;
  if (t < 128) sStat[t] = 0.f;
  {
    const int lr = t >> 4, k4 = (t & 15) * 4;
    const int kt = k4 >> 5, lanew = lr + (((k4>>3)&3)<<4), j0 = k4 & 7;
    #pragma unroll
    for (int i = 0; i < 4; ++i){
      int r = lr + i*16, gr = row0 + r;
      ushort4 pm; pm.x = 0; pm.y = 0; pm.z = 0; pm.w = 0;
      float4 vh = make_float4(0.f,0.f,0.f,0.f);
      if (gr < N_){
        pm = *reinterpret_cast<const ushort4*>(mbuf + (size_t)gr*64 + k4);
        vh = ldg4(hsrc + (size_t)gr*64 + k4);
      }
      ushort4 ph; ph.x=f2bf(vh.x); ph.y=f2bf(vh.y); ph.z=f2bf(vh.z); ph.w=f2bf(vh.w);
      *reinterpret_cast<ushort4*>(&sMf[((i*2+kt)*64 + lanew)*8 + j0]) = pm;
      *reinterpret_cast<ushort4*>(&sHf[((i*2+kt)*64 + lanew)*8 + j0]) = ph;
      sH[r][k4+0]=vh.x; sH[r][k4+1]=vh.y; sH[r][k4+2]=vh.z; sH[r][k4+3]=vh.w;
    }
  }
  __syncthreads();
  const int w = t >> 6, l = t & 63, q = l >> 4, b = l & 15;
  f32x4 aI[12], aH[12];
  #pragma unroll
  for (int nt = 0; nt < 12; ++nt){ aI[nt] = (f32x4){0.f,0.f,0.f,0.f}; aH[nt] = (f32x4){0.f,0.f,0.f,0.f}; }
  bf16x8 am0 = *reinterpret_cast<bf16x8*>(&sMf[((w*2+0)*64 + l)*8]);
  bf16x8 am1 = *reinterpret_cast<bf16x8*>(&sMf[((w*2+1)*64 + l)*8]);
  bf16x8 ah0 = *reinterpret_cast<bf16x8*>(&sHf[((w*2+0)*64 + l)*8]);
  bf16x8 ah1 = *reinterpret_cast<bf16x8*>(&sHf[((w*2+1)*64 + l)*8]);
  #pragma unroll
  for (int nt = 0; nt < 12; ++nt){
    bf16x8 bI0 = *reinterpret_cast<const bf16x8*>(fI + (size_t)((nt*2+0)*64 + l)*8);
    bf16x8 bI1 = *reinterpret_cast<const bf16x8*>(fI + (size_t)((nt*2+1)*64 + l)*8);
    bf16x8 bH0 = *reinterpret_cast<const bf16x8*>(fH + (size_t)((nt*2+0)*64 + l)*8);
    bf16x8 bH1 = *reinterpret_cast<const bf16x8*>(fH + (size_t)((nt*2+1)*64 + l)*8);
    aI[nt] = __builtin_amdgcn_mfma_f32_16x16x32_bf16(am0, bI0, aI[nt], 0, 0, 0);
    aI[nt] = __builtin_amdgcn_mfma_f32_16x16x32_bf16(am1, bI1, aI[nt], 0, 0, 0);
    aH[nt] = __builtin_amdgcn_mfma_f32_16x16x32_bf16(ah0, bH0, aH[nt], 0, 0, 0);
    aH[nt] = __builtin_amdgcn_mfma_f32_16x16x32_bf16(ah1, bH1, aH[nt], 0, 0, 0);
  }
  float s1[4] = {0.f,0.f,0.f,0.f}, s2[4] = {0.f,0.f,0.f,0.f};
  #pragma unroll
  for (int tt = 0; tt < 4; ++tt){
    int c = tt*16 + b;
    float bir = bih[c], biz = bih[64+c], bin = bih[128+c];
    float bhr = bhh[c], bhz = bhh[64+c], bhn = bhh[128+c];
    #pragma unroll
    for (int r = 0; r < 4; ++r){
      int row = w*16 + q*4 + r, gr = row0 + row;
      float rg = sigmoidf_(aI[tt][r]   + bir + aH[tt][r]   + bhr);
      float zg = sigmoidf_(aI[tt+4][r] + biz + aH[tt+4][r] + bhz);
      float ng = tanhf(aI[tt+8][r] + bin + rg*(aH[tt+8][r] + bhn));
      float ho = sH[row][c];
      float hv = (1.f - zg)*ng + zg*ho;
      if (gr < N_){
        hbuf[(size_t)gr*64 + c] = hv;
        s1[tt] += hv; s2[tt] += hv*hv;
      }
    }
  }
  #pragma unroll
  for (int tt = 0; tt < 4; ++tt){
    float v = s1[tt];
    v += __shfl_xor(v, 16); v += __shfl_xor(v, 32);
    float u = s2[tt];
    u += __shfl_xor(u, 16); u += __shfl_xor(u, 32);
    if (q == 0){
      atomicAdd(&sStat[tt*16 + b], v);
      atomicAdd(&sStat[64 + tt*16 + b], u);
    }
  }
  __syncthreads();
  if (t < 128) atomicAdd(&bn_stats[t], sStat[t]);
}

// out = [frag slots 0..5 | bn(hbuf)] @ Wlin + blin via MFMA
__global__ __launch_bounds__(256) void k_final(
    const unsigned short* __restrict__ ff, const float* __restrict__ hbuf,
    const float* __restrict__ bn_stats,     // slot 5
    const float* __restrict__ gamma, const float* __restrict__ beta,
    const unsigned short* __restrict__ fL, const float* __restrict__ blin,
    float* __restrict__ out)
{
  __shared__ short sAf[8*64*8];
  __shared__ float sSc[64], sSh[64];
  const int t = threadIdx.x;
  const int row0 = blockIdx.x * 64;
  if (t < 64){
    float mu  = bn_stats[t] * (1.0f/30000.0f);
    float var = bn_stats[64+t] * (1.0f/30000.0f) - mu*mu;
    float rs = rsqrtf(var + 1e-5f);
    float sc = gamma[5*64 + t] * rs;
    sSc[t] = sc;
    sSh[t] = beta[5*64 + t] - mu*sc;
  }
  __syncthreads();
  const int w = t >> 6, l = t & 63, q = l >> 4, b = l & 15;
  const int lr = t >> 4, k4 = (t & 15) * 4;
  const int kt = k4 >> 5, lanew = lr + (((k4>>3)&3)<<4), j0 = k4 & 7;
  // stage slot 6 = bn(hbuf)
  {
    #pragma unroll
    for (int i = 0; i < 4; ++i){
      int r = lr + i*16, gr = row0 + r;
      float4 v = make_float4(0.f,0.f,0.f,0.f);
      if (gr < N_){
        v = ldg4(hbuf + (size_t)gr*64 + k4);
        v.x = fmaf(v.x, sSc[k4+0], sSh[k4+0]);
        v.y = fmaf(v.y, sSc[k4+1], sSh[k4+1]);
        v.z = fmaf(v.z, sSc[k4+2], sSh[k4+2]);
        v.w = fmaf(v.w, sSc[k4+3], sSh[k4+3]);
      }
      ushort4 pk; pk.x=f2bf(v.x); pk.y=f2bf(v.y); pk.z=f2bf(v.z); pk.w=f2bf(v.w);
      *reinterpret_cast<ushort4*>(&sAf[((i*2+kt)*64 + lanew)*8 + j0]) = pk;
    }
  }
  __syncthreads();
  f32x4 acc[4];
  #pragma unroll
  for (int nt = 0; nt < 4; ++nt) acc[nt] = (f32x4){0.f,0.f,0.f,0.f};
  const unsigned short* fb = ff + (size_t)blockIdx.x*4096;
  #pragma unroll
  for (int kc = 0; kc < 6; ++kc){
    const unsigned short* fs = fb + (size_t)kc*GB_*4096;
    bf16x8 a0 = *reinterpret_cast<const bf16x8*>(fs + (w*2+0)*512 + l*8);
    bf16x8 a1 = *reinterpret_cast<const bf16x8*>(fs + (w*2+1)*512 + l*8);
    #pragma unroll
    for (int nt = 0; nt < 4; ++nt){
      bf16x8 b0 = *reinterpret_cast<const bf16x8*>(fL + (size_t)((nt*14 + kc*2+0)*64 + l)*8);
      bf16x8 b1 = *reinterpret_cast<const bf16x8*>(fL + (size_t)((nt*14 + kc*2+1)*64 + l)*8);
      acc[nt] = __builtin_amdgcn_mfma_f32_16x16x32_bf16(a0, b0, acc[nt], 0, 0, 0);
      acc[nt] = __builtin_amdgcn_mfma_f32_16x16x32_bf16(a1, b1, acc[nt], 0, 0, 0);
    }
  }
  {
    bf16x8 a0 = *reinterpret_cast<bf16x8*>(&sAf[((w*2+0)*64 + l)*8]);
    bf16x8 a1 = *reinterpret_cast<bf16x8*>(&sAf[((w*2+1)*64 + l)*8]);
    #pragma unroll
    for (int nt = 0; nt < 4; ++nt){
      bf16x8 b0 = *reinterpret_cast<const bf16x8*>(fL + (size_t)((nt*14 + 12)*64 + l)*8);
      bf16x8 b1 = *reinterpret_cast<const bf16x8*>(fL + (size_t)((nt*14 + 13)*64 + l)*8);
      acc[nt] = __builtin_amdgcn_mfma_f32_16x16x32_bf16(a0, b0, acc[nt], 0, 0, 0);
      acc[nt] = __builtin_amdgcn_mfma_f32_16x16x32_bf16(a1, b1, acc[nt], 0, 0, 0);
    }
  }
  #pragma unroll
  for (int nt = 0; nt < 4; ++nt){
    int col = nt*16 + b;
    float bl = blin[col];
    #pragma unroll
    for (int r = 0; r < 4; ++r){
      int gr = row0 + w*16 + q*4 + r;
      if (gr < N_) out[(size_t)gr*64 + col] = acc[nt][r] + bl;
    }
  }
}

// ---------------- launch ----------------

extern "C" void kernel_launch(void* const* d_in, const int* in_sizes, int n_in,
                              void* d_out, int out_size, void* d_ws, size_t ws_size,
                              hipStream_t stream) {
  const float* x        = (const float*)d_in[0];
  const int*   ei       = (const int*)  d_in[1];
  const float* edge_attr= (const float*)d_in[2];
  const float* Wg       = (const float*)d_in[3];
  const float* bg       = (const float*)d_in[4];
  const float* a_src    = (const float*)d_in[5];
  const float* a_dst    = (const float*)d_in[6];
  const float* We       = (const float*)d_in[7];
  const float* a_edge   = (const float*)d_in[8];
  const float* Wih      = (const float*)d_in[9];
  const float* Whh      = (const float*)d_in[10];
  const float* bih      = (const float*)d_in[11];
  const float* bhh      = (const float*)d_in[12];
  const float* gamma    = (const float*)d_in[13];
  const float* beta     = (const float*)d_in[14];
  const float* Wlin     = (const float*)d_in[15];
  const float* blin     = (const float*)d_in[16];
  float* out = (float*)d_out;

  char* w = (char*)d_ws;
  auto alloc = [&](size_t bytes) -> void* {
    void* p = (void*)w;
    w += (bytes + 255) & ~(size_t)255;
    return p;
  };
  int*   row_ptr = (int*)  alloc((size_t)(N_+1)*4);
  int*   deg     = (int*)  alloc((size_t)N_*4);
  int*   cursor  = (int*)  alloc((size_t)N_*4);
  int*   partial = (int*)  alloc(128*4);
  int*   src_s   = (int*)  alloc((size_t)E_*4);
  int*   dst_s   = (int*)  alloc((size_t)E_*4);
  float* el_s    = (float*)alloc((size_t)E_*3*4);
  float* att_s   = (float*)alloc((size_t)E_*3*4);
  float* Pw      = (float*)alloc(48*4);
  unsigned short* fG = (unsigned short*)alloc(12288*2);
  unsigned short* fI = (unsigned short*)alloc(12288*2);
  unsigned short* fH = (unsigned short*)alloc(12288*2);
  unsigned short* fL = (unsigned short*)alloc(28672*2);
  unsigned short* xw = (unsigned short*)alloc((size_t)N_*192*2);   // 3 planes N*64
  unsigned short* ffrag = (unsigned short*)alloc((size_t)6*GB_*4096*2);
  float* asrc    = (float*)alloc((size_t)N_*3*4);
  float* adst    = (float*)alloc((size_t)N_*3*4);
  unsigned short* mbuf = (unsigned short*)alloc((size_t)N_*64*2);
  float* hbuf    = (float*)alloc((size_t)N_*64*4);
  float* bn_stats= (float*)alloc(768*4);        // 6 slots of 128

  const int EB = (E_ + 255)/256;       // 1172

  k_wfrag  <<<258 + SCB, 256, 0, stream>>>(Wg, Wih, Whh, Wlin, We, a_edge,
                                           fG, fI, fH, fL, Pw, deg, bn_stats);
  k_hist   <<<EB, 256, 0, stream>>>(ei, deg);
  k_scanA  <<<SCB, 256, 0, stream>>>(deg, partial);
  k_scanB  <<<1, 128, 0, stream>>>(partial, row_ptr);
  k_scanC  <<<SCB, 256, 0, stream>>>(deg, partial, row_ptr, cursor);
  k_scatter<<<EB, 256, 0, stream>>>(ei, edge_attr, Pw, cursor, src_s, dst_s, el_s);

  for (int step = 0; step < 6; ++step){
    const float* hsrc = (step == 0) ? x : hbuf;
    k_xw <<<GB_, 256, 0, stream>>>(hsrc,
                                   bn_stats + (size_t)(step > 0 ? step-1 : 0)*128,
                                   gamma, beta, step-1, step > 0 ? 1 : 0,
                                   fG, a_src, a_dst, xw, asrc, adst,
                                   ffrag + (size_t)step*GB_*4096);
    k_att<<<EB, 256, 0, stream>>>(src_s, dst_s, el_s, asrc, adst, att_s);
    k_agg<<<(N_+3)/4, 256, 0, stream>>>(row_ptr, src_s, att_s, xw, bg, mbuf);
    k_gru<<<GB_, 256, 0, stream>>>(mbuf, hsrc, hbuf, fI, fH, bih, bhh,
                                   bn_stats + (size_t)step*128);
  }
  k_final<<<GB_, 256, 0, stream>>>(ffrag, hbuf, bn_stats + 5*128,
                                   gamma, beta, fL, blin, out);
}